// Round 1
// baseline (119.832 us; speedup 1.0000x reference)
//
#include <hip/hip_runtime.h>
#include <hip/hip_bf16.h>

// SpanV2 combo-table decomposition, round 11.
// Changes vs r10:
//  1. combo split 2x along m-rows: 352 blocks (2 per (b,s)), halved per-block
//     critical path, LDS 50->37 KB, better CU coverage (176 blocks left 80 CUs idle).
//  2. pack2 now single v_cvt_pk_bf16_f32 (was 9-op manual RNE bit-twiddle).
//  3. bucket build moved to prep as 16 per-batch blocks owning their batch:
//     no global atomics, no bucketCnt zero-init job, pb is pure MFMA (288 blocks).

#define NB 16
#define NH 768
#define NV 11
#define NL 25
#define CAP 768          // bucket capacity (expected ~372 spans per (b,s))

typedef __attribute__((ext_vector_type(8))) short frag8;
typedef __attribute__((ext_vector_type(4))) float f32x4;

__device__ __forceinline__ unsigned short f2bf(float f) {
    unsigned int u = __float_as_uint(f);
    u = (u + 0x7FFFu + ((u >> 16) & 1u)) >> 16;  // RNE
    return (unsigned short)u;
}
// packed RNE f32x2 -> bf16x2 in one instruction (gfx950)
__device__ __forceinline__ unsigned int pack2(float lo, float hi) {
    unsigned int r;
    asm("v_cvt_pk_bf16_f32 %0, %1, %2" : "=v"(r) : "v"(lo), "v"(hi));
    return r;
}
__device__ __forceinline__ float bflo(unsigned int u) { return __uint_as_float(u << 16); }
__device__ __forceinline__ float bfhi(unsigned int u) { return __uint_as_float(u & 0xFFFF0000u); }

// Fragment-ordered layouts (shorts):
//  W1F[nt(48)][kg(48)][ln(16)][q(4)][8]
//  W2F[kc(24)][nt(2)][ln(16)][q(4)][8]
//  HSA[mt(12)][kc(24)][ln(16)][q(4)][8]

// ---------------- Kernel 1: prep (+ bucket build) ----------------
#define TST 68
__global__ __launch_bounds__(256) void prep_kernel(
    const float* __restrict__ hs, const float* __restrict__ W1,
    const float* __restrict__ W2, const float* __restrict__ wemb,
    const int* __restrict__ spans,
    unsigned short* __restrict__ W1F, unsigned short* __restrict__ W2F,
    unsigned short* __restrict__ HSA, unsigned short* __restrict__ PWb,
    int* __restrict__ bucketCnt, int* __restrict__ bucketIdx)
{
    __shared__ float T[64 * TST];
    __shared__ int cntL[NV];
    const int job = blockIdx.x, tid = threadIdx.x;

    if (job < 288) {
        const int x = job / 12, y = job - x * 12;
        const int k0 = x * 64, n0 = y * 64;
        #pragma unroll
        for (int p = 0; p < 4; ++p) {
            int kl = (tid >> 4) + p * 16;
            int n4 = tid & 15;
            *(float4*)&T[kl * TST + n4 * 4] =
                *(const float4*)&W1[(size_t)(k0 + kl) * NH + n0 + n4 * 4];
        }
        __syncthreads();
        const int n = tid >> 2, kgl = tid & 3;
        const int nt = y * 4 + (n >> 4), ln = n & 15;
        #pragma unroll
        for (int half = 0; half < 2; ++half) {
            const int kk = kgl * 16 + half * 8;
            unsigned int o[4];
            #pragma unroll
            for (int i = 0; i < 4; ++i) {
                float a = T[(kk + 2 * i) * TST + n];
                float b = T[(kk + 2 * i + 1) * TST + n];
                o[i] = pack2(a, b);
            }
            const int kg = x * 2 + (kk >> 5);
            const int q = (kk >> 3) & 3;
            *(uint4*)&W1F[((((size_t)nt * 48 + kg) * 16 + ln) * 4 + q) * 8] =
                make_uint4(o[0], o[1], o[2], o[3]);
        }
    } else if (job < 300) {
        const int y = job - 288;
        const int kcl = tid >> 7, nt = (tid >> 6) & 1, ln = (tid >> 2) & 15, q = tid & 3;
        const int n2 = nt * 16 + ln;
        const int k = y * 64 + kcl * 32 + q * 8;
        unsigned int o[4];
        #pragma unroll
        for (int i = 0; i < 4; ++i) {
            float a = (n2 < NL) ? W2[(size_t)(k + 2 * i) * NL + n2] : 0.0f;
            float b = (n2 < NL) ? W2[(size_t)(k + 2 * i + 1) * NL + n2] : 0.0f;
            o[i] = pack2(a, b);
        }
        *(uint4*)&W2F[((((size_t)(y * 2 + kcl)) * 2 + nt) * 16 + ln) * 32 + q * 8] =
            make_uint4(o[0], o[1], o[2], o[3]);
    } else if (job < 312) {
        const int y = job - 300;
        const int n = y * 64 + (tid & 63);
        const int vg = tid >> 6;
        float acc[3] = {0.f, 0.f, 0.f};
        for (int k = 0; k < 150; k += 2) {
            float w1a = W1[(size_t)(1536 + k) * NH + n];
            float w1b = W1[(size_t)(1537 + k) * NH + n];
            #pragma unroll
            for (int j = 0; j < 3; ++j) {
                int v = vg + j * 4; int vs = (v < NV) ? v : 0;
                acc[j] += wemb[vs * 150 + k] * w1a + wemb[vs * 150 + k + 1] * w1b;
            }
        }
        #pragma unroll
        for (int j = 0; j < 3; ++j) {
            int v = vg + j * 4;
            if (v < NV) PWb[(size_t)v * NH + n] = f2bf(acc[j]);
        }
    } else if (job < 324) {
        const int mt = job - 312;
        #pragma unroll
        for (int it = 0; it < 6; ++it) {
            int u = it * 256 + tid;
            int kc = u >> 6, ln = (u >> 2) & 15, q = u & 3;
            int m = mt * 16 + ln;
            int b = m / 12, v = m - 12 * b;
            unsigned int o[4] = {0, 0, 0, 0};
            if (v < NV) {
                const float* p = hs + ((size_t)(b * 512 + v)) * NH + kc * 32 + q * 8;
                float4 a = *(const float4*)p;
                float4 c = *(const float4*)(p + 4);
                o[0] = pack2(a.x, a.y); o[1] = pack2(a.z, a.w);
                o[2] = pack2(c.x, c.y); o[3] = pack2(c.z, c.w);
            }
            *(uint4*)&HSA[((((size_t)mt * 24 + kc) * 16 + ln) * 4 + q) * 8] =
                make_uint4(o[0], o[1], o[2], o[3]);
        }
    } else {
        // bucket build: one block owns one batch b -> no global atomics,
        // no zero-init dependency. 4096 spans, LDS counters only.
        const int b = job - 324;
        if (tid < NV) cntL[tid] = 0;
        __syncthreads();
        const int* sp = spans + (size_t)b * 4096 * 3;
        for (int i = tid; i < 4096; i += 256) {
            int s = sp[i * 3 + 0];
            int e = sp[i * 3 + 1];
            int w = sp[i * 3 + 2];
            int slot = atomicAdd(&cntL[s], 1);
            if (slot < CAP)
                bucketIdx[((size_t)b * NV + s) * CAP + slot] =
                    (((b << 12) + i) << 7) | (e * NV + w);
        }
        __syncthreads();
        if (tid < NV) bucketCnt[b * NV + tid] = cntL[tid];
    }
}

// ---------------- Kernel 2: PS/PE precompute (pure MFMA) ----------------
__global__ __launch_bounds__(256) void pb_kernel(
    const unsigned short* __restrict__ HSA, const unsigned short* __restrict__ W1F,
    const float* __restrict__ b1,
    float* __restrict__ PS, unsigned short* __restrict__ PEb)
{
    const int tid = threadIdx.x;
    const int wave = tid >> 6, lane = tid & 63, q = lane >> 4, ln = lane & 15;
    const int job = blockIdx.x * 4 + wave;       // 0..1151
    const int part = job >= 576;
    const int j2 = job - part * 576;
    const int nt = j2 / 12;
    const int mt = j2 - nt * 12;

    const unsigned short* aP = HSA + (size_t)mt * 24 * 512 + ln * 32 + q * 8;
    const unsigned short* bP = W1F + ((size_t)nt * 48 + part * 24) * 512 + ln * 32 + q * 8;

    f32x4 acc;
    #pragma unroll
    for (int r = 0; r < 4; ++r) acc[r] = 0.0f;
    #pragma unroll 6
    for (int kc = 0; kc < 24; ++kc) {
        frag8 aF = *(const frag8*)(aP + kc * 512);
        frag8 bF = *(const frag8*)(bP + kc * 512);
        acc = __builtin_amdgcn_mfma_f32_16x16x32_bf16(aF, bF, acc, 0, 0, 0);
    }

    const int n = nt * 16 + ln;
    const float bb = part ? 0.0f : b1[n];
    #pragma unroll
    for (int r = 0; r < 4; ++r) {
        int m = mt * 16 + q * 4 + r;
        int b = m / 12, v = m - 12 * b;
        if (v < NV) {
            if (part)
                PEb[((size_t)(b * NV + v)) * NH + n] = f2bf(acc[r]);
            else
                PS[((size_t)(b * NV + v)) * NH + n] = acc[r] + bb;
        }
    }
}

// ---------------- Kernel 3: combo + scatter (2 blocks per (b,s)) ----------------
#define PEST 776   // ushort row stride (768+8)
#define CST 28     // Cs col stride (25+3)
__global__ __launch_bounds__(256) void combo_kernel(
    const float* __restrict__ PS, const unsigned short* __restrict__ PEb,
    const unsigned short* __restrict__ PWb, const unsigned short* __restrict__ W2F,
    const float* __restrict__ b2, const int* __restrict__ bucketCnt,
    const int* __restrict__ bucketIdx, float* __restrict__ out)
{
    __shared__ float baseL[NH];                  // 3 KB fp32
    __shared__ unsigned short peL[6 * PEST];     // 9.1 KB (this half's 6 e-rows)
    __shared__ unsigned short pwL[NV * PEST];    // 17.1 KB
    __shared__ float Cs[64 * CST];               // 7.2 KB

    const int tid = threadIdx.x;
    const int wave = tid >> 6, lane = tid & 63, q = lane >> 4, ln = lane & 15;
    const int blk = blockIdx.x;
    const int bs = blk >> 1;                     // (b,s) pair index
    const int h = blk & 1;                       // row-half: rows [64h, 64h+64)
    const int b = bs / NV, s = bs - NV * b;

    int cnt = bucketCnt[bs];                     // hoisted scalar load
    if (cnt > CAP) cnt = CAP;

    const float* ps = PS + (size_t)(b * NV + s) * NH;
    for (int i = tid; i < 192; i += 256)
        *(float4*)&baseL[i * 4] = *(const float4*)&ps[i * 4];
    for (int i = tid; i < 6 * 96; i += 256) {
        int v = i / 96, j = i - 96 * v;          // global e = 5h + v
        *(uint4*)&peL[v * PEST + j * 8] =
            *(const uint4*)&PEb[((size_t)(b * NV + 5 * h + v)) * NH + j * 8];
    }
    for (int i = tid; i < NV * 96; i += 256) {
        int v = i / 96, j = i - 96 * v;
        *(uint4*)&pwL[v * PEST + j * 8] =
            *(const uint4*)&PWb[(size_t)v * NH + j * 8];
    }

    // one m-tile per wave: global tile = h*4 + wave, rows tile*16..tile*16+15
    const int tile = h * 4 + wave;
    const int m = tile * 16 + ln;
    const int me = (m < 121) ? m : 120;
    const int eI = (me * 373) >> 12;             // me/11 for me<=120
    const int wI = me - NV * eI;
    const int eLoc = eI - 5 * h;                 // 0..5 within this half's peL

    f32x4 acc[2];
    #pragma unroll
    for (int nt = 0; nt < 2; ++nt)
        #pragma unroll
        for (int r = 0; r < 4; ++r) acc[nt][r] = 0.0f;

    const unsigned short* w2p = W2F + ln * 32 + q * 8;

    __syncthreads();

    for (int ch = 0; ch < 12; ++ch) {
        #pragma unroll
        for (int kt = 0; kt < 2; ++kt) {
            const int kk = ch * 64 + kt * 32 + q * 8;
            union { float4 v[2]; float f[8]; } cb;
            cb.v[0] = *(const float4*)&baseL[kk];
            cb.v[1] = *(const float4*)&baseL[kk + 4];
            uint4 pu = *(const uint4*)&peL[eLoc * PEST + kk];
            uint4 wu = *(const uint4*)&pwL[wI * PEST + kk];
            unsigned int o[4];
            #pragma unroll
            for (int t = 0; t < 4; ++t) {
                unsigned int p  = ((const unsigned int*)&pu)[t];
                unsigned int ww = ((const unsigned int*)&wu)[t];
                float a0 = bflo(p) + bflo(ww) + cb.f[2 * t];
                float a1 = bfhi(p) + bfhi(ww) + cb.f[2 * t + 1];
                o[t] = pack2(fmaxf(a0, 0.f), fmaxf(a1, 0.f));
            }
            union { uint4 u; frag8 f; } cv;
            cv.u = make_uint4(o[0], o[1], o[2], o[3]);
            #pragma unroll
            for (int nt = 0; nt < 2; ++nt) {
                frag8 bf = *(const frag8*)(w2p + ((ch * 2 + kt) * 2 + nt) * 512);
                acc[nt] = __builtin_amdgcn_mfma_f32_16x16x32_bf16(
                    cv.f, bf, acc[nt], 0, 0, 0);
            }
        }
    }

    // ---- epilogue: C (+b2) -> LDS (local rows 0..63 of this half) ----
    __syncthreads();
    #pragma unroll
    for (int nt = 0; nt < 2; ++nt) {
        int n = nt * 16 + ln;
        if (n < NL) {
            float bias = b2[n];
            #pragma unroll
            for (int r = 0; r < 4; ++r) {
                int mm = tile * 16 + q * 4 + r;
                if (mm < 121)
                    Cs[(mm - 64 * h) * CST + n] = acc[nt][r] + bias;
            }
        }
    }
    __syncthreads();

    // ---- scatter: this block's spans whose row falls in [64h, 64h+64) ----
    const int total = cnt * NL;
    const int* bk = bucketIdx + (size_t)bs * CAP;
    const int rbase = 64 * h;
    for (int j = tid; j < total; j += 256) {
        int sp = (int)(((unsigned)j * 5243u) >> 17);     // j/25 for j<131072
        int c = j - sp * NL;
        int packed = bk[sp];
        int row = (packed & 127) - rbase;
        if ((unsigned)row < 64u) {
            int span = packed >> 7;
            out[(size_t)span * NL + c] = Cs[row * CST + c];
        }
    }
}

extern "C" void kernel_launch(void* const* d_in, const int* in_sizes, int n_in,
                              void* d_out, int out_size, void* d_ws, size_t ws_size,
                              hipStream_t stream) {
    const float* hs    = (const float*)d_in[0];
    const int*   spans = (const int*)d_in[1];
    const float* wemb  = (const float*)d_in[2];
    const float* W1    = (const float*)d_in[3];
    const float* b1    = (const float*)d_in[4];
    const float* W2    = (const float*)d_in[5];
    const float* b2    = (const float*)d_in[6];
    float* out = (float*)d_out;

    float* PS = (float*)d_ws;                                    // 135168 f
    unsigned short* PEb = (unsigned short*)(PS + NB * NV * NH);  // 135168 sh
    unsigned short* PWb = PEb + NB * NV * NH;                    // 8448 sh
    unsigned short* W2F = PWb + NV * NH;                         // 24576 sh
    unsigned short* W1F = W2F + 24 * 2 * 512;                    // 1179648 sh
    unsigned short* HSA = W1F + (size_t)48 * 48 * 512;           // 147456 sh
    int* bucketCnt = (int*)(HSA + (size_t)12 * 24 * 512);        // 176 int
    int* bucketIdx = bucketCnt + 256;                            // 176*CAP int
    // total ~4.5 MB

    prep_kernel<<<dim3(340), dim3(256), 0, stream>>>(
        hs, W1, W2, wemb, spans, W1F, W2F, HSA, PWb, bucketCnt, bucketIdx);
    pb_kernel<<<dim3(288), dim3(256), 0, stream>>>(
        HSA, W1F, b1, PS, PEb);
    combo_kernel<<<dim3(NB * NV * 2), dim3(256), 0, stream>>>(
        PS, PEb, PWb, W2F, b2, bucketCnt, bucketIdx, out);
}